// Round 16
// baseline (119.551 us; speedup 1.0000x reference)
//
#include <hip/hip_runtime.h>
#include <hip/hip_bf16.h>
#include <math.h>

#define LWAV   480000
#define NBATCH 32
#define TOUT   1000
#define NMEL   64
#define PSTR   576
#define SPECW  1024
#define SLEN   120256      // stream length = XPADL/4
#define SBYTES 7696384u    // 32*120256*2

// workspace layout (bytes), 16B-aligned
#define XS_OFF  0u           // 4 streams x SBYTES = 30,785,536
#define WEO_OFF 30785536u    // 1024 rows x 256 x 2B = 524,288 -> 31,309,824
#define WMT_OFF 31309824u    // 64*576*2 = 73,728 -> 31,383,552
#define W2_OFF  31383552u    // 16 rows x 256 x 2B = 8,192 -> 31,391,744
#define PW_OFF  31391744u    // 32000*576*2 -> 68,255,744
#define LM_OFF  68255744u    // 32000*64*4 -> 76,447,744

typedef __attribute__((ext_vector_type(8))) __bf16 bf16x8;
typedef __attribute__((ext_vector_type(8))) unsigned short ushort8;
typedef __attribute__((ext_vector_type(4))) float  f32x4;

__device__ __forceinline__ void gload16(const void* g, void* l) {
  __builtin_amdgcn_global_load_lds((const __attribute__((address_space(1))) void*)g,
                                   (__attribute__((address_space(3))) void*)l, 16, 0, 0);
}
#define WAIT_VM(n)  asm volatile("s_waitcnt vmcnt(" #n ")" ::: "memory")
#define BAR() __builtin_amdgcn_s_barrier()

__device__ __forceinline__ float bf2f(unsigned short u) {
  return __uint_as_float((unsigned)u << 16);
}

// ---------------- prepass: 4-stream split + radix-4 weight tables ----------------
#define NH1 (NBATCH * (SLEN / 8))   // 481,024 (each thread: 32 xpad samples -> 8/stream)
#define NH2 ((1024 * 256) / 8)      // 32,768  (wEO4 rows: r*256 + p*128 + j)
#define NH3 ((NMEL * PSTR) / 8)     // 4,608
#define NH4 (16 * 256 / 8)          // 512 (bins 128/384 stream tables)

__global__ void prep_kernel(const float* __restrict__ wav,
                            const float* __restrict__ wstft,
                            const float* __restrict__ mf,
                            unsigned char* __restrict__ ws) {
  __hip_bfloat16* weo = (__hip_bfloat16*)(ws + WEO_OFF);
  __hip_bfloat16* wmt = (__hip_bfloat16*)(ws + WMT_OFF);
  __hip_bfloat16* w2  = (__hip_bfloat16*)(ws + W2_OFF);
  int idx = blockIdx.x * blockDim.x + threadIdx.x;
  if (idx < NH1) {
    int b  = idx / (SLEN / 8);
    int gg = idx - b * (SLEN / 8);     // xpad positions [32gg, 32gg+32)
    const float* src = wav + (size_t)b * LWAV;
    __hip_bfloat16 tS[4][8];
    if (gg >= 16 && gg <= 15015) {     // fully interior
      const float4* p = (const float4*)(src + 32 * gg - 512);
#pragma unroll
      for (int u = 0; u < 8; ++u) {
        float4 v = p[u];
        tS[0][u] = __float2bfloat16(v.x);
        tS[1][u] = __float2bfloat16(v.y);
        tS[2][u] = __float2bfloat16(v.z);
        tS[3][u] = __float2bfloat16(v.w);
      }
    } else {
#pragma unroll
      for (int i = 0; i < 32; ++i) {
        int q = 32 * gg + i;
        int s = q - 512;
        if (s < 0) s = -s;
        else if (s >= LWAV) s = 2 * (LWAV - 1) - s;
        tS[i & 3][i >> 2] = __float2bfloat16(src[s]);
      }
    }
#pragma unroll
    for (int r = 0; r < 4; ++r)
      *(uint4*)(ws + XS_OFF + (unsigned)r * SBYTES + ((size_t)b * SLEN + 8 * gg) * 2) =
          *(const uint4*)tS[r];
  } else if (idx < NH1 + NH2) {
    int v = idx - NH1;
    int rowt = v >> 5;                // 0..1023 = r*256 + p*128 + j
    int mseg = (v & 31) * 8;
    int r = rowt >> 8, rem = rowt & 255;
    int p = rem >> 7, j = rem & 127;
    __hip_bfloat16 t[8];
#pragma unroll
    for (int h = 0; h < 8; ++h) {
      int m = mseg + h;
      float wv = wstft[4 * m + r];            // window sample w[4m+r]
      int q = (j * m) & 255;                  // exact mod-256 angle reduction
      float ang = (float)q * 0.024543693f;    // 2*pi/256
      t[h] = __float2bfloat16(p == 0 ? wv * cosf(ang) : -wv * sinf(ang));
    }
    *(uint4*)(weo + (size_t)rowt * 256 + mseg) = *(const uint4*)t;
  } else if (idx < NH1 + NH2 + NH3) {
    int j = idx - NH1 - NH2;
    int n = j / (PSTR / 8);
    int k0 = (j - n * (PSTR / 8)) * 8;
    for (int k = k0; k < k0 + 8; ++k)
      wmt[n * PSTR + k] = __float2bfloat16(k < 513 ? mf[k * NMEL + n] : 0.0f);
  } else if (idx < NH1 + NH2 + NH3 + NH4) {
    int g = idx - NH1 - NH2 - NH3;    // 0..511
    int rowW = g >> 5;                // 0..15 = (bin*2+p)*4 + r
    int m0g = (g & 31) * 8;
    int r = rowW & 3, p = (rowW >> 2) & 1, bin = rowW >> 3;
    int srow = bin ? (p ? 897 : 384) : (p ? 641 : 128);
    __hip_bfloat16 t[8];
#pragma unroll
    for (int h = 0; h < 8; ++h)
      t[h] = __float2bfloat16(wstft[(size_t)srow * 1024 + 4 * (m0g + h) + r]);
    *(uint4*)(w2 + (size_t)rowW * 256 + m0g) = *(const uint4*)t;
  }
}

// ---------------- bins 128 & 384 helper: writes pw[m][128], pw[m][384] ----------------
__launch_bounds__(256, 2)
__global__ void p2_kernel(unsigned char* __restrict__ ws) {
  __hip_bfloat16* pw = (__hip_bfloat16*)(ws + PW_OFF);
  const int tid  = threadIdx.x;
  const int l16  = tid & 15;
  const int fidx = blockIdx.x * 16 + (tid >> 4);
  const int b = fidx / 1000, t = fidx - b * 1000;
  const int r  = l16 >> 2;
  const int qr = l16 & 3;

  const unsigned char* x  = ws + XS_OFF + (unsigned)r * SBYTES +
                            ((size_t)b * SLEN + 120 * (size_t)t + qr * 64) * 2;
  const unsigned char* wc1 = ws + W2_OFF + (size_t)(0 * 4 + r) * 512 + qr * 128;
  const unsigned char* ws1 = ws + W2_OFF + (size_t)(1 * 4 + r) * 512 + qr * 128;
  const unsigned char* wc3 = ws + W2_OFF + (size_t)(2 * 4 + r) * 512 + qr * 128;
  const unsigned char* ws3 = ws + W2_OFF + (size_t)(3 * 4 + r) * 512 + qr * 128;

  float c1 = 0.f, s1 = 0.f, c3 = 0.f, s3 = 0.f;
#pragma unroll
  for (int ch = 0; ch < 8; ++ch) {
    ushort8 xv = *(const ushort8*)(x + ch * 16);
    ushort8 a1 = *(const ushort8*)(wc1 + ch * 16);
    ushort8 b1 = *(const ushort8*)(ws1 + ch * 16);
    ushort8 a3 = *(const ushort8*)(wc3 + ch * 16);
    ushort8 b3 = *(const ushort8*)(ws3 + ch * 16);
#pragma unroll
    for (int e = 0; e < 8; ++e) {
      float fx = bf2f(xv[e]);
      c1 += fx * bf2f(a1[e]);
      s1 += fx * bf2f(b1[e]);
      c3 += fx * bf2f(a3[e]);
      s3 += fx * bf2f(b3[e]);
    }
  }
#pragma unroll
  for (int d = 1; d < 16; d <<= 1) {
    c1 += __shfl_xor(c1, d);
    s1 += __shfl_xor(s1, d);
    c3 += __shfl_xor(c3, d);
    s3 += __shfl_xor(s3, d);
  }
  if (l16 == 0) {
    size_t base = ((size_t)b * TOUT + t) * PSTR;
    pw[base + 128] = __float2bfloat16(c1 * c1 + s1 * s1);
    pw[base + 384] = __float2bfloat16(c3 * c3 + s3 * s3);
  }
}

// ---------------- STFT radix-4 GEMM: BM=128, 32 j x 8 comps, K=256/stream, BK=32 ----
// 1000 blocks (250 m x 4 j-tiles), 512 thr, 8 waves (4M x 2N): wave = 32m x
// (16j x 8 comps). Triple-buffered 48KB sets (A: 128 rows x 256B [4 streams x
// 4 chunks]; B: 256 rows x 64B), 1 barrier + vmcnt(6)/ktile (R10-proven
// skeleton), 8 ktiles. Epilogue: 4-bin twiddle combine {j,256-j,256+j,512-j}.
#define STFT_NWG 1000
__launch_bounds__(512, 1)
__global__ void stft_kernel(unsigned char* __restrict__ ws) {
  __shared__ __align__(16) unsigned char lds[147456];   // 3 x (A 32768 + B 16384)
  __hip_bfloat16* pw = (__hip_bfloat16*)(ws + PW_OFF);

  const int tid  = threadIdx.x;
  const int lane = tid & 63;
  const int w    = tid >> 6;
  const int wm   = w >> 1;      // 0..3 (32-frame quarter)
  const int wn   = w & 1;       // 0..1 (16-j half)

  // bijective XCD-chunked swizzle (nwg=1000: q=125, r=0), j-tile fastest
  const int orig = blockIdx.x;
  const int wg = (orig & 7) * 125 + (orig >> 3);
  const int j0 = (wg & 3) * 32;
  const int m0 = (wg >> 2) * 128;

  // ---- A staging: 4 gloads/thread/ktile. A row = 256B = 16 slots of 16B;
  // logical slot s = stream*4 + kchunk; phys = s ^ (row&15). ----
  const unsigned char* srcA[4];
#pragma unroll
  for (int i = 0; i < 4; ++i) {
    int idxs = i * 512 + tid;
    int row = idxs >> 4;
    int s = (idxs & 15) ^ (row & 15);
    int r = s >> 2, c = s & 3;
    int m = m0 + row;
    int bb = m / 1000, tt = m - bb * 1000;
    srcA[i] = ws + XS_OFF + (unsigned)r * SBYTES +
              ((size_t)bb * SLEN + 120 * (size_t)tt + c * 8) * 2;
  }
  // ---- B staging: 2 gloads/thread/ktile. B row = 64B = 4 slots; logical
  // chunk = phys ^ ((row>>1)&3); global row = r*256 + p*128 + (j0 + j'). ----
  const unsigned char* srcB[2];
#pragma unroll
  for (int i = 0; i < 2; ++i) {
    int idxb = i * 512 + tid;          // 0..1023
    int row = idxb >> 2;               // 0..255 = r*64 + p*32 + j'
    int c = (idxb & 3) ^ ((row >> 1) & 3);
    int grow = (row >> 6) * 256 + ((row >> 5) & 1) * 128 + j0 + (row & 31);
    srcB[i] = ws + WEO_OFF + (size_t)grow * 512 + c * 16;
  }

#define STG(cb, kt) do {                                                        \
    gload16(srcA[0] + (size_t)(kt) * 64, lds + (cb) * 49152 + (0 * 512 + tid) * 16); \
    gload16(srcA[1] + (size_t)(kt) * 64, lds + (cb) * 49152 + (1 * 512 + tid) * 16); \
    gload16(srcA[2] + (size_t)(kt) * 64, lds + (cb) * 49152 + (2 * 512 + tid) * 16); \
    gload16(srcA[3] + (size_t)(kt) * 64, lds + (cb) * 49152 + (3 * 512 + tid) * 16); \
    gload16(srcB[0] + (size_t)(kt) * 64, lds + (cb) * 49152 + 32768 + (0 * 512 + tid) * 16); \
    gload16(srcB[1] + (size_t)(kt) * 64, lds + (cb) * 49152 + 32768 + (1 * 512 + tid) * 16); \
  } while (0)

  // ---- fragment read bases ----
  const int l15 = lane & 15, lc = lane >> 4;
  // A: row = wm*32 + mf*16 + l15 (row&15 == l15); phys slot = (r*4+lc) ^ l15
  const unsigned char* aBase = lds + (wm * 32 + l15) * 256;
  int paX[4];
#pragma unroll
  for (int r = 0; r < 4; ++r) paX[r] = (((r * 4 + lc) ^ l15) << 4);
  // B: row = r*64 + p*32 + wn*16 + l15; phys chunk = lc ^ ((l15>>1)&3)
  const unsigned char* bBase = lds + 32768 + ((wn * 16 + l15) << 6) +
                               ((lc ^ ((l15 >> 1) & 3)) << 4);

  bf16x8 af[2][4], bf[4][2];
  f32x4 acc[2][8];   // [mf][r*2+p]
#pragma unroll
  for (int a = 0; a < 2; ++a)
#pragma unroll
    for (int b2 = 0; b2 < 8; ++b2) acc[a][b2] = (f32x4){0.f, 0.f, 0.f, 0.f};

  // prologue: stage k0->buf0, k1->buf1 (12 loads); retire k0
  STG(0, 0);
  STG(1, 1);
  WAIT_VM(6);
  BAR();

#pragma unroll
  for (int kt = 0; kt < 8; ++kt) {
    const int cur = kt % 3;
    if (kt + 2 < 8) STG((kt + 2) % 3, kt + 2);
#pragma unroll
    for (int mf = 0; mf < 2; ++mf)
#pragma unroll
      for (int r = 0; r < 4; ++r)
        af[mf][r] = *(const bf16x8*)(aBase + cur * 49152 + mf * 4096 + paX[r]);
#pragma unroll
    for (int r = 0; r < 4; ++r) {
      bf[r][0] = *(const bf16x8*)(bBase + cur * 49152 + r * 4096);
      bf[r][1] = *(const bf16x8*)(bBase + cur * 49152 + r * 4096 + 2048);
    }
    __builtin_amdgcn_s_setprio(1);
#pragma unroll
    for (int mf = 0; mf < 2; ++mf)
#pragma unroll
      for (int r = 0; r < 4; ++r) {
        acc[mf][2 * r]     = __builtin_amdgcn_mfma_f32_16x16x32_bf16(
            af[mf][r], bf[r][0], acc[mf][2 * r], 0, 0, 0);
        acc[mf][2 * r + 1] = __builtin_amdgcn_mfma_f32_16x16x32_bf16(
            af[mf][r], bf[r][1], acc[mf][2 * r + 1], 0, 0, 0);
      }
    __builtin_amdgcn_s_setprio(0);
    if (kt < 6) { WAIT_VM(6); BAR(); }
    else if (kt == 6) { WAIT_VM(0); BAR(); }
  }

  // ---- epilogue: 4-bin twiddle combine ----
  // X_k = S0 + W^k(S1 + W^k(S2 + W^k S3)); tk = e^{-i pi j/512} = (ct,-st).
  // k=j: w=tk, S as-is | k=256-j: w=(st,-ct), S conj | k=256+j: w=(-st,-ct),
  // S as-is | k=512-j: w=(-ct,-st), S conj.
  {
    const int j = j0 + wn * 16 + l15;   // 0..127
    const float th = (float)j * 0.0061359233f;   // pi/512
    const float ct = cosf(th), st = sinf(th);
    const float wr4[4] = { ct, st, -st, -ct };
    const float wi4[4] = { -st, -ct, -ct, -st };
    const int   bins[4] = { j, 256 - j, 256 + j, 512 - j };
#pragma unroll
    for (int mf = 0; mf < 2; ++mf)
#pragma unroll
      for (int r4 = 0; r4 < 4; ++r4) {
        const int m = m0 + wm * 32 + mf * 16 + lc * 4 + r4;
        const float C0 = acc[mf][0][r4], S0 = acc[mf][1][r4];
        const float C1 = acc[mf][2][r4], S1 = acc[mf][3][r4];
        const float C2 = acc[mf][4][r4], S2 = acc[mf][5][r4];
        const float C3 = acc[mf][6][r4], S3 = acc[mf][7][r4];
        size_t base = (size_t)m * PSTR;
#pragma unroll
        for (int bi = 0; bi < 4; ++bi) {
          const float sg = (bi == 1 || bi == 3) ? -1.f : 1.f;
          const float wr = wr4[bi], wi = wi4[bi];
          // Horner: t = S3; t = S2 + w t; t = S1 + w t; X = S0 + w t
          float tr = C3, ti = sg * S3;
          float ur = C2 + (wr * tr - wi * ti);
          float ui = sg * S2 + (wr * ti + wi * tr);
          tr = C1 + (wr * ur - wi * ui);
          ti = sg * S1 + (wr * ui + wi * ur);
          ur = C0 + (wr * tr - wi * ti);
          ui = sg * S0 + (wr * ti + wi * tr);
          pw[base + bins[bi]] = __float2bfloat16(ur * ur + ui * ui);
        }
      }
  }
}

// ---------------- mel GEMM (K=576, BM=64) + log10 epilogue ----------------
__launch_bounds__(256, 4)
__global__ void mel_kernel(unsigned char* __restrict__ ws) {
  __shared__ __align__(16) unsigned char sA[64 * 128];
  __shared__ __align__(16) unsigned char sBt[64 * 128];
  const unsigned char* pwb  = ws + PW_OFF;
  const unsigned char* wmtb = ws + WMT_OFF;
  float* lm = (float*)(ws + LM_OFF);

  const int tid = threadIdx.x;
  const int lane = tid & 63;
  const int wid  = tid >> 6;
  const int m0 = blockIdx.x * 64;

  const int strow = tid >> 3;
  const int scol  = (tid & 7) << 4;

  const unsigned char* aptr[2];
  const unsigned char* bptr[2];
  unsigned char* aldst[2];
  unsigned char* bldst[2];
#pragma unroll
  for (int jj = 0; jj < 2; ++jj) {
    int rr = jj * 32 + strow;
    aptr[jj] = pwb + (size_t)(m0 + rr) * (PSTR * 2) + (scol ^ ((rr & 7) << 4));
    bptr[jj] = wmtb + (size_t)rr * (PSTR * 2) + (scol ^ ((rr & 7) << 4));
    aldst[jj] = &sA [jj * 4096 + wid * 1024];
    bldst[jj] = &sBt[jj * 4096 + wid * 1024];
  }

  f32x4 acc[4];
#pragma unroll
  for (int fr = 0; fr < 4; ++fr) acc[fr] = (f32x4){0.f, 0.f, 0.f, 0.f};

  for (int kk = 0; kk < PSTR; kk += 64) {
    __syncthreads();
#pragma unroll
    for (int jj = 0; jj < 2; ++jj) gload16(aptr[jj] + (size_t)kk * 2, aldst[jj]);
#pragma unroll
    for (int jj = 0; jj < 2; ++jj) gload16(bptr[jj] + (size_t)kk * 2, bldst[jj]);
    __syncthreads();
#pragma unroll
    for (int ks = 0; ks < 2; ++ks) {
      const int kby = ks * 64 + ((lane >> 4) << 4);
      bf16x8 af, bfr[4];
      {
        int rr = wid * 16 + (lane & 15);
        af = *(const bf16x8*)&sA[rr * 128 + (kby ^ ((rr & 7) << 4))];
      }
#pragma unroll
      for (int fr = 0; fr < 4; ++fr) {
        int rr = fr * 16 + (lane & 15);
        bfr[fr] = *(const bf16x8*)&sBt[rr * 128 + (kby ^ ((rr & 7) << 4))];
      }
#pragma unroll
      for (int fr = 0; fr < 4; ++fr)
        acc[fr] = __builtin_amdgcn_mfma_f32_16x16x32_bf16(af, bfr[fr], acc[fr], 0, 0, 0);
    }
  }

  const int col = lane & 15;
  const int rg  = lane >> 4;
#pragma unroll
  for (int fr = 0; fr < 4; ++fr) {
    int n = fr * 16 + col;
#pragma unroll
    for (int rr = 0; rr < 4; ++rr) {
      int mrow = wid * 16 + rg * 4 + rr;
      float v = acc[fr][rr];
      lm[(size_t)(m0 + mrow) * NMEL + n] = 10.0f * log10f(fmaxf(v, 1e-10f));
    }
  }
}

// ---------------- bilinear (time-axis only) interp ----------------
__global__ void interp_kernel(const unsigned char* __restrict__ ws, float* __restrict__ out) {
  const float* lm = (const float*)(ws + LM_OFF);
  int idx = blockIdx.x * blockDim.x + threadIdx.x;
  if (idx >= NBATCH * SPECW * 16) return;
  int m4 = idx & 15;
  int h  = (idx >> 4) & (SPECW - 1);
  int b  = idx >> 14;
  const float scale = (float)(999.0 / 1023.0);
  float pos = (float)h * scale;
  int i0 = (int)floorf(pos);
  if (i0 > TOUT - 1) i0 = TOUT - 1;
  float wgt = pos - (float)i0;
  int i1 = i0 + 1;
  if (i1 > TOUT - 1) i1 = TOUT - 1;
  const float4* r0 = (const float4*)(lm + ((size_t)b * TOUT + i0) * NMEL);
  const float4* r1 = (const float4*)(lm + ((size_t)b * TOUT + i1) * NMEL);
  float4 a = r0[m4], c = r1[m4];
  float4 o;
  o.x = a.x * (1.0f - wgt) + c.x * wgt;
  o.y = a.y * (1.0f - wgt) + c.y * wgt;
  o.z = a.z * (1.0f - wgt) + c.z * wgt;
  o.w = a.w * (1.0f - wgt) + c.w * wgt;
  ((float4*)out)[idx] = o;
}

extern "C" void kernel_launch(void* const* d_in, const int* in_sizes, int n_in,
                              void* d_out, int out_size, void* d_ws, size_t ws_size,
                              hipStream_t stream) {
  (void)in_sizes; (void)n_in; (void)out_size; (void)ws_size;
  const float* wav   = (const float*)d_in[0];
  const float* wstft = (const float*)d_in[1];
  const float* mf    = (const float*)d_in[2];
  unsigned char* ws  = (unsigned char*)d_ws;
  float* out = (float*)d_out;

  const int tot = NH1 + NH2 + NH3 + NH4;   // 518,912
  prep_kernel<<<(tot + 255) / 256, 256, 0, stream>>>(wav, wstft, mf, ws);
  stft_kernel<<<STFT_NWG, 512, 0, stream>>>(ws);
  p2_kernel<<<2000, 256, 0, stream>>>(ws);
  mel_kernel<<<500, 256, 0, stream>>>(ws);
  interp_kernel<<<(NBATCH * SPECW * 16) / 256, 256, 0, stream>>>(ws, out);
}

// Round 17
// 90.374 us; speedup vs baseline: 1.3228x; 1.3228x over previous
//
#include <hip/hip_runtime.h>
#include <hip/hip_bf16.h>
#include <math.h>

#define LWAV   480000
#define XHALF  240512      // xpad length / 2
#define NBATCH 32
#define TOUT   1000
#define NMEL   64
#define PSTR   576
#define SPECW  1024

// workspace layout (bytes), 16B-aligned
#define XPE_OFF  0u           // 32*240512*2 = 15,392,768
#define XPO_OFF  15392768u    // 32*240512*2 -> 30,785,536
#define WEO_OFF  30785536u    // 1024*512*2  -> 31,834,112
#define WMT_OFF  31834112u    // 64*576*2    -> 31,907,840
#define PW_OFF   31907840u    // 32000*576*2 -> 68,771,840
#define LM_OFF   68771840u    // 32000*64*4  -> 76,963,840
#define W256_OFF 76963840u    // 1024*2      -> 76,965,888

typedef __attribute__((ext_vector_type(8))) __bf16 bf16x8;
typedef __attribute__((ext_vector_type(8))) unsigned short ushort8;
typedef __attribute__((ext_vector_type(4))) float  f32x4;

__device__ __forceinline__ void gload16(const void* g, void* l) {
  __builtin_amdgcn_global_load_lds((const __attribute__((address_space(1))) void*)g,
                                   (__attribute__((address_space(3))) void*)l, 16, 0, 0);
}
#define WAIT_VM(n)  asm volatile("s_waitcnt vmcnt(" #n ")" ::: "memory")
#define BAR() __builtin_amdgcn_s_barrier()

__device__ __forceinline__ float bf2f(unsigned short u) {
  return __uint_as_float((unsigned)u << 16);
}

// ---------------- prepass: even/odd split + radix-2 weight tables ----------------
#define NG1 (NBATCH * (XHALF / 8))   // 962,048
#define NG2 ((1024 * 512) / 8)       // 65,536
#define NG3 ((NMEL * PSTR) / 8)      // 4,608
#define NG4 (1024 / 8)               // 128

__global__ void prep_kernel(const float* __restrict__ wav,
                            const float* __restrict__ wstft,
                            const float* __restrict__ mf,
                            unsigned char* __restrict__ ws) {
  __hip_bfloat16* xpE = (__hip_bfloat16*)(ws + XPE_OFF);
  __hip_bfloat16* xpO = (__hip_bfloat16*)(ws + XPO_OFF);
  __hip_bfloat16* weo = (__hip_bfloat16*)(ws + WEO_OFF);
  __hip_bfloat16* wmt = (__hip_bfloat16*)(ws + WMT_OFF);
  __hip_bfloat16* w256 = (__hip_bfloat16*)(ws + W256_OFF);
  int idx = blockIdx.x * blockDim.x + threadIdx.x;
  if (idx < NG1) {
    int b = idx / (XHALF / 8);
    int g = idx - b * (XHALF / 8);       // xpad positions [16g, 16g+16)
    const float* src = wav + (size_t)b * LWAV;
    __hip_bfloat16 e[8], o[8];
    if (g >= 32 && g <= 30030) {
      const float4* p = (const float4*)(src + 16 * g - 512);
#pragma unroll
      for (int u = 0; u < 4; ++u) {
        float4 v = p[u];
        e[2 * u]     = __float2bfloat16(v.x);
        o[2 * u]     = __float2bfloat16(v.y);
        e[2 * u + 1] = __float2bfloat16(v.z);
        o[2 * u + 1] = __float2bfloat16(v.w);
      }
    } else {
      for (int i = 0; i < 16; ++i) {
        int q = 16 * g + i;
        int s = q - 512;
        if (s < 0) s = -s;
        else if (s >= LWAV) s = 2 * (LWAV - 1) - s;
        __hip_bfloat16 v = __float2bfloat16(src[s]);
        if (i & 1) o[i >> 1] = v; else e[i >> 1] = v;
      }
    }
    *(uint4*)(xpE + (size_t)b * XHALF + 8 * g) = *(const uint4*)e;
    *(uint4*)(xpO + (size_t)b * XHALF + 8 * g) = *(const uint4*)o;
  } else if (idx < NG1 + NG2) {
    int v = idx - NG1;
    int row = v >> 6;                 // 0..1023 = comp*256 + j
    int mseg = (v & 63) * 8;
    int comp = row >> 8, j = row & 255;
    __hip_bfloat16 t[8];
    if (comp < 2) {
      const float4* srow = (const float4*)(wstft + (size_t)(comp == 0 ? j : 513 + j) * 1024 + 2 * mseg);
#pragma unroll
      for (int u = 0; u < 4; ++u) {
        float4 vv = srow[u];
        t[2 * u]     = __float2bfloat16(vv.x);
        t[2 * u + 1] = __float2bfloat16(vv.z);
      }
    } else {
      const float4* w0 = (const float4*)(wstft + 2 * mseg);
#pragma unroll
      for (int u = 0; u < 4; ++u) {
        float4 wwv = w0[u];
        float wo[2] = {wwv.y, wwv.w};
#pragma unroll
        for (int h = 0; h < 2; ++h) {
          int mm = mseg + 2 * u + h;
          int q = (j * mm) & 511;
          float ang = (float)q * 0.012271846f;    // 2*pi/512
          float val = (comp == 2) ? wo[h] * cosf(ang) : -wo[h] * sinf(ang);
          t[2 * u + h] = __float2bfloat16(val);
        }
      }
    }
    *(uint4*)(weo + (size_t)row * 512 + mseg) = *(const uint4*)t;
  } else if (idx < NG1 + NG2 + NG3) {
    int j = idx - NG1 - NG2;
    int n = j / (PSTR / 8);
    int k0 = (j - n * (PSTR / 8)) * 8;
    for (int k = k0; k < k0 + 8; ++k)
      wmt[n * PSTR + k] = __float2bfloat16(k < 513 ? mf[k * NMEL + n] : 0.0f);
  } else if (idx < NG1 + NG2 + NG3 + NG4) {
    int j = idx - NG1 - NG2 - NG3;
    int part = j >> 6;
    int m0 = (j & 63) * 8;
    __hip_bfloat16 t[8];
#pragma unroll
    for (int h = 0; h < 8; ++h) {
      int m = m0 + h;
      float v = part == 0 ? wstft[(size_t)256 * 1024 + 2 * m]
                          : wstft[(size_t)769 * 1024 + 2 * m + 1];
      t[h] = __float2bfloat16(v);
    }
    *(uint4*)(w256 + part * 512 + m0) = *(const uint4*)t;
  }
}

// ---------------- STFT radix-2 GEMM (R10-proven) + folded p256 ----
// Blocks [0,500): BM=256, 64 j x {Ec,Es,Oc,Os}, K=512, BK=32. Triple-buffered
// 48KB sets, 1 barrier + vmcnt(6) per ktile, 2-deep prefetch, twiddle epilogue.
// Blocks [500,1500): bin-256 dot products (32 frames/block, 16 lanes/frame).
#define STFT_NWG 500
__launch_bounds__(512, 1)
__global__ void stft_kernel(unsigned char* __restrict__ ws) {
  __shared__ __align__(16) unsigned char lds[147456];   // 3 x (A 32768 + B 16384)
  __hip_bfloat16* pw = (__hip_bfloat16*)(ws + PW_OFF);

  // ---------- folded p256 path ----------
  if (blockIdx.x >= STFT_NWG) {
    const int tid = threadIdx.x;
    const int l16 = tid & 15;
    const int fidx = (blockIdx.x - STFT_NWG) * 32 + (tid >> 4);
    if (fidx < NBATCH * TOUT) {
      const int b = fidx / 1000, t = fidx - b * 1000;
      const unsigned short* xe = (const unsigned short*)(ws + XPE_OFF) +
          (size_t)b * XHALF + 240 * (size_t)t + l16 * 32;
      const unsigned short* xo = (const unsigned short*)(ws + XPO_OFF) +
          (size_t)b * XHALF + 240 * (size_t)t + l16 * 32;
      const unsigned short* we = (const unsigned short*)(ws + W256_OFF) + l16 * 32;
      const unsigned short* wo = (const unsigned short*)(ws + W256_OFF) + 512 + l16 * 32;
      ushort8 ev[4], ov[4], wev[4], wov[4];
#pragma unroll
      for (int q = 0; q < 4; ++q) {
        ev[q]  = *(const ushort8*)(xe + q * 8);
        ov[q]  = *(const ushort8*)(xo + q * 8);
        wev[q] = *(const ushort8*)(we + q * 8);
        wov[q] = *(const ushort8*)(wo + q * 8);
      }
      float dc = 0.f, dsn = 0.f;
#pragma unroll
      for (int q = 0; q < 4; ++q)
#pragma unroll
        for (int u = 0; u < 8; ++u) {
          dc  += bf2f(ev[q][u]) * bf2f(wev[q][u]);
          dsn += bf2f(ov[q][u]) * bf2f(wov[q][u]);
        }
#pragma unroll
      for (int d = 1; d < 16; d <<= 1) {
        dc  += __shfl_xor(dc, d);
        dsn += __shfl_xor(dsn, d);
      }
      if (l16 == 0)
        pw[((size_t)b * TOUT + t) * PSTR + 256] = __float2bfloat16(dc * dc + dsn * dsn);
    }
    return;
  }

  // ---------- stft GEMM path (verbatim R10) ----------
  const int tid  = threadIdx.x;
  const int lane = tid & 63;
  const int w    = tid >> 6;
  const int wm   = w >> 2;
  const int wc   = w & 3;

  // bijective XCD-chunked swizzle (nwg=500: q=62, r=4), j-tile fastest
  const int orig = blockIdx.x;
  const int q8 = STFT_NWG / 8, r8 = STFT_NWG % 8;
  const int xcd = orig & 7;
  const int wg = (xcd < r8 ? xcd * (q8 + 1) : r8 * (q8 + 1) + (xcd - r8) * q8) + (orig >> 3);
  const int j0 = (wg & 3) * 64;
  const int m0 = (wg >> 2) * 256;

  // staging sources (per-thread, pre-swizzled; +64B per ktile)
  const unsigned char* gsA[4];
  const unsigned char* gsB[2];
#pragma unroll
  for (int i = 0; i < 4; ++i) {
    int r = (w * 4 + i) * 8 + (lane >> 3);
    int q = lane & 7;
    int l1 = q ^ (r & 7);
    int m = m0 + r;
    int bb = m / 1000, tt = m - bb * 1000;
    size_t fbase = ((size_t)bb * XHALF + 240 * (size_t)tt) * 2;
    gsA[i] = (l1 < 4) ? (ws + XPE_OFF + fbase + l1 * 16)
                      : (ws + XPO_OFF + fbase + (l1 - 4) * 16);
  }
#pragma unroll
  for (int i = 0; i < 2; ++i) {
    int r = (w * 2 + i) * 16 + (lane >> 2);
    int q = lane & 3;
    int l2 = q ^ ((r >> 1) & 3);
    int comp = (r >> 4) & 3;
    int jv = j0 + (r >> 6) * 16 + (r & 15);
    gsB[i] = ws + WEO_OFF + ((size_t)(comp * 256 + jv) * 512) * 2 + l2 * 16;
  }

#define STG(c, kt) do {                                                          \
    gload16(gsA[0] + (size_t)(kt) * 64, lds + (c) * 49152 + (w * 4 + 0) * 1024); \
    gload16(gsA[1] + (size_t)(kt) * 64, lds + (c) * 49152 + (w * 4 + 1) * 1024); \
    gload16(gsA[2] + (size_t)(kt) * 64, lds + (c) * 49152 + (w * 4 + 2) * 1024); \
    gload16(gsA[3] + (size_t)(kt) * 64, lds + (c) * 49152 + (w * 4 + 3) * 1024); \
    gload16(gsB[0] + (size_t)(kt) * 64, lds + (c) * 49152 + 32768 + (w * 2 + 0) * 1024); \
    gload16(gsB[1] + (size_t)(kt) * 64, lds + (c) * 49152 + 32768 + (w * 2 + 1) * 1024); \
  } while (0)

  // fragment read bases (lane-invariant XOR; row&7 == l15&7, (row>>1)&3 == (l15>>1)&3)
  const int l15 = lane & 15, lc = lane >> 4;
  const int swA = (lc ^ (l15 & 7)) << 4;
  const unsigned char* aeB = lds + (wm * 128 + l15) * 128 + swA;
  const unsigned char* aoB = lds + (wm * 128 + l15) * 128 + (swA ^ 64);
  const int swB = (lc ^ ((l15 >> 1) & 3)) << 4;
  const unsigned char* bB = lds + 32768 + (wc * 64 + l15) * 64 + swB;

  bf16x8 ae[8], ao[8], bfr[4];
  f32x4 acc[8][4];
#pragma unroll
  for (int a = 0; a < 8; ++a)
#pragma unroll
    for (int b2 = 0; b2 < 4; ++b2) acc[a][b2] = (f32x4){0.f, 0.f, 0.f, 0.f};

  // prologue: stage k0->buf0, k1->buf1 (12 loads); retire k0
  STG(0, 0);
  STG(1, 1);
  WAIT_VM(6);
  BAR();

#pragma unroll
  for (int kt = 0; kt < 16; ++kt) {
    const int cur = kt % 3;
    if (kt + 2 < 16) STG((kt + 2) % 3, kt + 2);
#pragma unroll
    for (int mf = 0; mf < 8; ++mf)
      ae[mf] = *(const bf16x8*)(aeB + cur * 49152 + mf * 2048);
#pragma unroll
    for (int nf = 0; nf < 4; ++nf)
      bfr[nf] = *(const bf16x8*)(bB + cur * 49152 + nf * 1024);
    __builtin_amdgcn_s_setprio(1);
#pragma unroll
    for (int mf = 0; mf < 8; ++mf) {
      acc[mf][0] = __builtin_amdgcn_mfma_f32_16x16x32_bf16(ae[mf], bfr[0], acc[mf][0], 0, 0, 0);
      acc[mf][1] = __builtin_amdgcn_mfma_f32_16x16x32_bf16(ae[mf], bfr[1], acc[mf][1], 0, 0, 0);
    }
    __builtin_amdgcn_s_setprio(0);
#pragma unroll
    for (int mf = 0; mf < 8; ++mf)
      ao[mf] = *(const bf16x8*)(aoB + cur * 49152 + mf * 2048);
    __builtin_amdgcn_s_setprio(1);
#pragma unroll
    for (int mf = 0; mf < 8; ++mf) {
      acc[mf][2] = __builtin_amdgcn_mfma_f32_16x16x32_bf16(ao[mf], bfr[2], acc[mf][2], 0, 0, 0);
      acc[mf][3] = __builtin_amdgcn_mfma_f32_16x16x32_bf16(ao[mf], bfr[3], acc[mf][3], 0, 0, 0);
    }
    __builtin_amdgcn_s_setprio(0);
    if (kt < 14) { WAIT_VM(6); BAR(); }
    else if (kt == 14) { WAIT_VM(0); BAR(); }
  }

  // epilogue: twiddle-combine -> power bins j and 512-j
  const int j = j0 + wc * 16 + l15;
  const float th = (float)j * 0.0061359233f;   // pi/512
  const float ct = cosf(th), st = sinf(th);
#pragma unroll
  for (int mf = 0; mf < 8; ++mf)
#pragma unroll
    for (int r = 0; r < 4; ++r) {
      int m = m0 + wm * 128 + mf * 16 + lc * 4 + r;
      float Ec = acc[mf][0][r], Es = acc[mf][1][r];
      float Oc = acc[mf][2][r], Os = acc[mf][3][r];
      float tOc = ct * Oc + st * Os;
      float tOs = ct * Os - st * Oc;
      float re1 = Ec + tOc, im1 = Es + tOs;
      float re2 = Ec - tOc, im2 = Es - tOs;
      pw[(size_t)m * PSTR + j]         = __float2bfloat16(re1 * re1 + im1 * im1);
      pw[(size_t)m * PSTR + (512 - j)] = __float2bfloat16(re2 * re2 + im2 * im2);
    }
}

// ---------------- mel GEMM (K=576, BM=64) + log10 epilogue ----------------
__launch_bounds__(256, 4)
__global__ void mel_kernel(unsigned char* __restrict__ ws) {
  __shared__ __align__(16) unsigned char sA[64 * 128];
  __shared__ __align__(16) unsigned char sBt[64 * 128];
  const unsigned char* pwb  = ws + PW_OFF;
  const unsigned char* wmtb = ws + WMT_OFF;
  float* lm = (float*)(ws + LM_OFF);

  const int tid = threadIdx.x;
  const int lane = tid & 63;
  const int wid  = tid >> 6;
  const int m0 = blockIdx.x * 64;

  const int strow = tid >> 3;
  const int scol  = (tid & 7) << 4;

  const unsigned char* aptr[2];
  const unsigned char* bptr[2];
  unsigned char* aldst[2];
  unsigned char* bldst[2];
#pragma unroll
  for (int jj = 0; jj < 2; ++jj) {
    int rr = jj * 32 + strow;
    aptr[jj] = pwb + (size_t)(m0 + rr) * (PSTR * 2) + (scol ^ ((rr & 7) << 4));
    bptr[jj] = wmtb + (size_t)rr * (PSTR * 2) + (scol ^ ((rr & 7) << 4));
    aldst[jj] = &sA [jj * 4096 + wid * 1024];
    bldst[jj] = &sBt[jj * 4096 + wid * 1024];
  }

  f32x4 acc[4];
#pragma unroll
  for (int fr = 0; fr < 4; ++fr) acc[fr] = (f32x4){0.f, 0.f, 0.f, 0.f};

  for (int kk = 0; kk < PSTR; kk += 64) {
    __syncthreads();
#pragma unroll
    for (int jj = 0; jj < 2; ++jj) gload16(aptr[jj] + (size_t)kk * 2, aldst[jj]);
#pragma unroll
    for (int jj = 0; jj < 2; ++jj) gload16(bptr[jj] + (size_t)kk * 2, bldst[jj]);
    __syncthreads();
#pragma unroll
    for (int ks = 0; ks < 2; ++ks) {
      const int kby = ks * 64 + ((lane >> 4) << 4);
      bf16x8 af, bfr[4];
      {
        int rr = wid * 16 + (lane & 15);
        af = *(const bf16x8*)&sA[rr * 128 + (kby ^ ((rr & 7) << 4))];
      }
#pragma unroll
      for (int fr = 0; fr < 4; ++fr) {
        int rr = fr * 16 + (lane & 15);
        bfr[fr] = *(const bf16x8*)&sBt[rr * 128 + (kby ^ ((rr & 7) << 4))];
      }
#pragma unroll
      for (int fr = 0; fr < 4; ++fr)
        acc[fr] = __builtin_amdgcn_mfma_f32_16x16x32_bf16(af, bfr[fr], acc[fr], 0, 0, 0);
    }
  }

  const int col = lane & 15;
  const int rg  = lane >> 4;
#pragma unroll
  for (int fr = 0; fr < 4; ++fr) {
    int n = fr * 16 + col;
#pragma unroll
    for (int rr = 0; rr < 4; ++rr) {
      int mrow = wid * 16 + rg * 4 + rr;
      float v = acc[fr][rr];
      lm[(size_t)(m0 + mrow) * NMEL + n] = 10.0f * log10f(fmaxf(v, 1e-10f));
    }
  }
}

// ---------------- bilinear (time-axis only) interp ----------------
__global__ void interp_kernel(const unsigned char* __restrict__ ws, float* __restrict__ out) {
  const float* lm = (const float*)(ws + LM_OFF);
  int idx = blockIdx.x * blockDim.x + threadIdx.x;
  if (idx >= NBATCH * SPECW * 16) return;
  int m4 = idx & 15;
  int h  = (idx >> 4) & (SPECW - 1);
  int b  = idx >> 14;
  const float scale = (float)(999.0 / 1023.0);
  float pos = (float)h * scale;
  int i0 = (int)floorf(pos);
  if (i0 > TOUT - 1) i0 = TOUT - 1;
  float wgt = pos - (float)i0;
  int i1 = i0 + 1;
  if (i1 > TOUT - 1) i1 = TOUT - 1;
  const float4* r0 = (const float4*)(lm + ((size_t)b * TOUT + i0) * NMEL);
  const float4* r1 = (const float4*)(lm + ((size_t)b * TOUT + i1) * NMEL);
  float4 a = r0[m4], c = r1[m4];
  float4 o;
  o.x = a.x * (1.0f - wgt) + c.x * wgt;
  o.y = a.y * (1.0f - wgt) + c.y * wgt;
  o.z = a.z * (1.0f - wgt) + c.z * wgt;
  o.w = a.w * (1.0f - wgt) + c.w * wgt;
  ((float4*)out)[idx] = o;
}

extern "C" void kernel_launch(void* const* d_in, const int* in_sizes, int n_in,
                              void* d_out, int out_size, void* d_ws, size_t ws_size,
                              hipStream_t stream) {
  (void)in_sizes; (void)n_in; (void)out_size; (void)ws_size;
  const float* wav   = (const float*)d_in[0];
  const float* wstft = (const float*)d_in[1];
  const float* mf    = (const float*)d_in[2];
  unsigned char* ws  = (unsigned char*)d_ws;
  float* out = (float*)d_out;

  const int tot = NG1 + NG2 + NG3 + NG4;
  prep_kernel<<<(tot + 255) / 256, 256, 0, stream>>>(wav, wstft, mf, ws);
  // blocks [0,500): radix-2 GEMM; blocks [500,1500): bin-256 dots (32 frames each)
  stft_kernel<<<STFT_NWG + 1000, 512, 0, stream>>>(ws);
  mel_kernel<<<500, 256, 0, stream>>>(ws);
  interp_kernel<<<(NBATCH * SPECW * 16) / 256, 256, 0, stream>>>(ws, out);
}